// Round 5
// baseline (2539.714 us; speedup 1.0000x reference)
//
#include <hip/hip_runtime.h>
#include <float.h>

#define NN 64000
#define BB 128
#define NPGc 500
#define EE 512000

// ---------------- threefry2x32, JAX partitionable path, key = (0,42) ----------------
__device__ __forceinline__ unsigned rotl32(unsigned x, unsigned r){ return (x<<r)|(x>>(32u-r)); }

__device__ __forceinline__ unsigned threefry_bits(unsigned idx){
  unsigned x0 = 0u, x1 = idx;
  const unsigned ks0 = 0u, ks1 = 42u, ks2 = 0u ^ 42u ^ 0x1BD11BDAu;
  x0 += ks0; x1 += ks1;
#define RND(r) { x0 += x1; x1 = rotl32(x1, r); x1 ^= x0; }
  RND(13u) RND(15u) RND(26u) RND(6u)   x0 += ks1; x1 += ks2 + 1u;
  RND(17u) RND(29u) RND(16u) RND(24u)  x0 += ks2; x1 += ks0 + 2u;
  RND(13u) RND(15u) RND(26u) RND(6u)   x0 += ks0; x1 += ks1 + 3u;
  RND(17u) RND(29u) RND(16u) RND(24u)  x0 += ks1; x1 += ks2 + 4u;
  RND(13u) RND(15u) RND(26u) RND(6u)   x0 += ks2; x1 += ks0 + 5u;
#undef RND
  return x0 ^ x1;
}

__device__ __forceinline__ float gumbel_of(unsigned idx){
  unsigned bits = threefry_bits(idx);
  float f = __uint_as_float((bits >> 9) | 0x3f800000u) - 1.0f;
  const float TINY = 1.17549435e-38f;
  float u = fmaxf(TINY, f + TINY);
  return -logf(-logf(u));   // precise logf: argmax must match ref bit-wise
}

__device__ __forceinline__ float fast_tanh(float x){
  // tanh(x) = 1 - 2/(exp(2x)+1); __expf err ~5e-7 abs, saturates correctly at +-inf
  return 1.0f - 2.0f/(__expf(2.0f*x) + 1.0f);
}

// ---------------- mask dtype detection ----------------
__global__ void maskdet_kernel(const unsigned* __restrict__ m, int* __restrict__ flag){
  if (threadIdx.x == 0){
    int isbool = 0;
    for (int i=0;i<256;i++){ if (m[i] > 1u){ isbool = 1; break; } }
    *flag = isbool;
  }
}

// ---------------- CSR build ----------------
__global__ void count_kernel(const int* __restrict__ dst, int* __restrict__ cnt){
  int e = blockIdx.x*256 + threadIdx.x;
  if (e < EE) atomicAdd(&cnt[dst[e]], 1);
}

__global__ __launch_bounds__(1024)
void scan_kernel(const int* __restrict__ cnt, int* __restrict__ off, int* __restrict__ cur){
  __shared__ int part[1024];
  int tid = threadIdx.x;
  const int chunk = 63;
  int base = tid*chunk;
  int sum = 0;
  for (int i=0;i<chunk;i++){ int n = base+i; if (n < NN) sum += cnt[n]; }
  part[tid] = sum;
  __syncthreads();
  for (int d=1; d<1024; d<<=1){
    int v = (tid >= d) ? part[tid-d] : 0;
    __syncthreads();
    part[tid] += v;
    __syncthreads();
  }
  int run = part[tid] - sum;
  for (int i=0;i<chunk;i++){
    int n = base+i;
    if (n < NN){ off[n] = run; cur[n] = run; run += cnt[n]; }
  }
  if (tid == 1023) off[NN] = run;
}

__global__ void fill_kernel(const int* __restrict__ src, const int* __restrict__ dst,
                            int* __restrict__ cur, int* __restrict__ csr){
  int e = blockIdx.x*256 + threadIdx.x;
  if (e < EE){
    int d = dst[e];
    int p = atomicAdd(&cur[d], 1);
    csr[p] = src[e];
  }
}

__global__ void dinv_kernel(const int* __restrict__ cnt, float* __restrict__ dinv){
  int n = blockIdx.x*256 + threadIdx.x;
  if (n < NN) dinv[n] = 1.0f/(float)(cnt[n]+1);
}

// ---------------- aggregation ----------------
__global__ void agg3_kernel(const float* __restrict__ x, const int* __restrict__ off,
                            const int* __restrict__ csr, const float* __restrict__ dinv,
                            float* __restrict__ xin0){
  int n = blockIdx.x*256 + threadIdx.x;
  if (n >= NN) return;
  float a0 = x[n*3], a1 = x[n*3+1], a2 = x[n*3+2];
  float s0 = a0, s1 = a1, s2 = a2;
  int e1 = off[n+1];
  for (int e = off[n]; e < e1; ++e){
    int s = csr[e];
    s0 += x[s*3]; s1 += x[s*3+1]; s2 += x[s*3+2];
  }
  float di = dinv[n];
  xin0[n*3]   = a0 + s0*di;
  xin0[n*3+1] = a1 + s1*di;
  xin0[n*3+2] = a2 + s2*di;
}

__global__ __launch_bounds__(256)
void agg128_kernel(const float* __restrict__ h, const int* __restrict__ off,
                   const int* __restrict__ csr, const float* __restrict__ dinv,
                   float* __restrict__ xin){
  int w = (blockIdx.x*256 + threadIdx.x) >> 6;
  int lane = threadIdx.x & 63;
  if (w >= NN) return;
  const float* hn = h + (size_t)w*128;
  float a0 = hn[lane], a1 = hn[lane+64];
  float s0 = a0, s1 = a1;              // self loop included in agg sum
  int e0 = off[w], e1 = off[w+1];
  for (int e = e0; e < e1; ++e){
    int s = csr[e];
    const float* hs = h + (size_t)s*128;
    s0 += hs[lane]; s1 += hs[lane+64];
  }
  float di = dinv[w];
  xin[(size_t)w*128 + lane]      = a0 + s0*di;
  xin[(size_t)w*128 + lane + 64] = a1 + s1*di;
}

// ---------------- layer-0 z (K=3) with BN stats ----------------
__global__ __launch_bounds__(256)
void z0_kernel(const float* __restrict__ xin0, const float* __restrict__ W,
               const float* __restrict__ bias, float* __restrict__ z,
               float* __restrict__ stats){
  __shared__ float xr[192];
  __shared__ float ssum[128], ssq[128];
  int t = threadIdx.x;
  int row0 = blockIdx.x*64;
  if (t < 192) xr[t] = xin0[(size_t)row0*3 + t];
  if (t < 128){ ssum[t]=0.f; ssq[t]=0.f; }
  int f = t & 127, rg = t >> 7;
  float w0 = W[f], w1 = W[128+f], w2 = W[256+f], bb = bias[f];
  __syncthreads();
  float s = 0.f, q = 0.f;
  for (int i=0;i<32;i++){
    int r = rg*32 + i;
    float y = bb + xr[r*3]*w0 + xr[r*3+1]*w1 + xr[r*3+2]*w2;
    z[(size_t)(row0+r)*128 + f] = y;
    s += y; q += y*y;
  }
  atomicAdd(&ssum[f], s); atomicAdd(&ssq[f], q);
  __syncthreads();
  if (t < 128){ atomicAdd(&stats[t], ssum[t]); atomicAdd(&stats[128+t], ssq[t]); }
}

__global__ void bnfin_kernel(const float* __restrict__ stats, const float* __restrict__ g,
                             const float* __restrict__ be, float* __restrict__ bnbuf){
  int f = threadIdx.x;
  float mu  = stats[f]     * (1.0f/NN);
  float var = stats[128+f] * (1.0f/NN) - mu*mu;
  float rsv = rsqrtf(var + 1e-5f);
  float sc  = g[f]*rsv;
  bnbuf[f]      = sc;
  bnbuf[128+f]  = be[f] - mu*sc;
}

// ---------------- fp32 linear: 128 rows x 128 out per block, 8x8 micro-tile ----------------
// POOLM: 0 none, 1 pool = y, 2 pool += y
template<int K, bool CATF, bool BNF, bool TANHF, bool STATSF, int POOLM>
__global__ __launch_bounds__(256, 4)
void linear_kernel(const float* X, const float* __restrict__ X2,
                   const float* __restrict__ W, const float* __restrict__ bias,
                   float* Y,
                   const float* __restrict__ bnsc, const float* __restrict__ bnsh,
                   float* __restrict__ stats, float* __restrict__ pool){
  __shared__ __align__(16) float xs[32][132];
  __shared__ __align__(16) float ws[32][132];
  __shared__ float ssum[128], ssq[128];
  const int t = threadIdx.x;
  const int row0 = blockIdx.x*128;
  const int cg = t & 15, rg = t >> 4;
  const int c0 = cg*8, r0 = rg*8;
  float acc[8][8];
#pragma unroll
  for (int r=0;r<8;r++)
#pragma unroll
    for (int c=0;c<8;c++) acc[r][c]=0.f;
  if (STATSF && t < 128){ ssum[t]=0.f; ssq[t]=0.f; }

  for (int kc=0; kc<K; kc+=32){
    __syncthreads();
    // xs stage: 32k x 128r ; lanes sweep k (coalesced global)
#pragma unroll
    for (int i=0;i<16;i++){
      int idx = t + 256*i;
      int k = idx & 31, r = idx >> 5;
      int gk = kc + k;
      int n = row0 + r;
      float v;
      if (CATF){
        v = (gk < 128) ? X[(size_t)n*128 + gk] : X2[(size_t)(n/NPGc)*128 + (gk-128)];
      } else {
        v = X[(size_t)n*K + gk];
      }
      if (BNF) v = fmaxf(0.f, v*bnsc[gk] + bnsh[gk]);
      xs[k][r] = v;
    }
    // ws stage: 32k x 128c ; lanes sweep c (coalesced global, conflict-free LDS)
#pragma unroll
    for (int i=0;i<16;i++){
      int idx = t + 256*i;
      int c = idx & 127, k = idx >> 7;
      ws[k][c] = W[(size_t)(kc+k)*128 + c];
    }
    __syncthreads();
#pragma unroll
    for (int k=0;k<32;k++){
      float4 xa = *(const float4*)&xs[k][r0];
      float4 xb = *(const float4*)&xs[k][r0+4];
      float4 wa = *(const float4*)&ws[k][c0];
      float4 wb = *(const float4*)&ws[k][c0+4];
      float xv[8] = {xa.x,xa.y,xa.z,xa.w,xb.x,xb.y,xb.z,xb.w};
      float wv[8] = {wa.x,wa.y,wa.z,wa.w,wb.x,wb.y,wb.z,wb.w};
#pragma unroll
      for (int r=0;r<8;r++)
#pragma unroll
        for (int c=0;c<8;c++)
          acc[r][c] += xv[r]*wv[c];
    }
  }
  float4 ba = *(const float4*)(bias + c0);
  float4 bb2 = *(const float4*)(bias + c0 + 4);
  float bv[8] = {ba.x,ba.y,ba.z,ba.w,bb2.x,bb2.y,bb2.z,bb2.w};
  float sc8[8], sq8[8];
#pragma unroll
  for (int c=0;c<8;c++){ sc8[c]=0.f; sq8[c]=0.f; }
#pragma unroll
  for (int r=0;r<8;r++){
    int n = row0 + r0 + r;
    float y[8];
#pragma unroll
    for (int c=0;c<8;c++){
      float v = acc[r][c] + bv[c];
      if (TANHF) v = fast_tanh(v);
      y[c] = v;
    }
    float4 y0; y0.x=y[0]; y0.y=y[1]; y0.z=y[2]; y0.w=y[3];
    float4 y1; y1.x=y[4]; y1.y=y[5]; y1.z=y[6]; y1.w=y[7];
    *(float4*)(Y + (size_t)n*128 + c0)     = y0;
    *(float4*)(Y + (size_t)n*128 + c0 + 4) = y1;
    if (POOLM == 1){
      *(float4*)(pool + (size_t)n*128 + c0)     = y0;
      *(float4*)(pool + (size_t)n*128 + c0 + 4) = y1;
    } else if (POOLM == 2){
      float4 p0 = *(const float4*)(pool + (size_t)n*128 + c0);
      float4 p1 = *(const float4*)(pool + (size_t)n*128 + c0 + 4);
      p0.x+=y[0]; p0.y+=y[1]; p0.z+=y[2]; p0.w+=y[3];
      p1.x+=y[4]; p1.y+=y[5]; p1.z+=y[6]; p1.w+=y[7];
      *(float4*)(pool + (size_t)n*128 + c0)     = p0;
      *(float4*)(pool + (size_t)n*128 + c0 + 4) = p1;
    }
    if (STATSF){
#pragma unroll
      for (int c=0;c<8;c++){ sc8[c]+=y[c]; sq8[c]+=y[c]*y[c]; }
    }
  }
  if (STATSF){
#pragma unroll
    for (int c=0;c<8;c++){
      atomicAdd(&ssum[c0+c], sc8[c]);
      atomicAdd(&ssq[c0+c],  sq8[c]);
    }
    __syncthreads();
    if (t < 128){
      atomicAdd(&stats[t],     ssum[t]);
      atomicAdd(&stats[128+t], ssq[t]);
    }
  }
}

// ---------------- graph pool (mean of node_pool per graph) ----------------
__global__ void gpool_kernel(const float* __restrict__ pool, float* __restrict__ gpool){
  int b = blockIdx.x, f = threadIdx.x;
  const float* p = pool + (size_t)b*NPGc*128 + f;
  float s = 0.f;
  for (int i=0;i<NPGc;i++) s += p[(size_t)i*128];
  gpool[(size_t)b*128 + f] = s * (1.0f/NPGc);
}

// ---------------- scores + mask + gumbel (queue-compacted) + online softmax + argmax --------
#define QCAP 1024

__global__ __launch_bounds__(256)
void scores_kernel(const float* __restrict__ A, const unsigned char* __restrict__ mask_u8,
                   const int* __restrict__ mask_i32, const int* __restrict__ mflag,
                   float* __restrict__ partials){
  __shared__ __align__(16) float as[128][68];
  __shared__ __align__(16) float ams[32][68];
  __shared__ float qs[QCAP];
  __shared__ int   qi[QCAP];
  __shared__ int   qcnt;
  // reduction arrays alias the queue (all drains complete before final reduction)
  float* rm  = qs;        // 256
  float* rs_ = qs + 256;  // 256
  float* rv  = qs + 512;  // 256
  float* rsc = qs + 768;  // 256
  int*   ri  = qi;        // 256
  const int t = threadIdx.x;
  const int b = blockIdx.y, tile = blockIdx.x;
  const int n0 = tile*64;
  const int cgc = t & 15, rgc = t >> 4;
  const int r0_ = rgc*4, c0 = cgc*4;
  const float* Ab = A + (size_t)b*NPGc*128;
  const unsigned gbase = (unsigned)b*250000u;
  const int isbool = *mflag;
  if (t == 0) qcnt = 0;

#pragma unroll
  for (int i=0;i<32;i++){
    int idx = t + 256*i;
    int k = idx & 127, r = idx >> 7;
    int n = n0 + r;
    as[k][r] = (n < NPGc) ? Ab[(size_t)n*128 + k] : 0.f;
  }

  float mrun = -1e30f, srun = 0.f, bval = -FLT_MAX, bsc = 0.f;
  int bidx = 0x7FFFFFFF;   // LOCAL (within-graph) action index

  for (int mc=0; mc<8; mc++){
    int m0 = mc*64;
    float acc[4][4];
#pragma unroll
    for (int i2=0;i2<4;i2++)
#pragma unroll
      for (int j=0;j<4;j++) acc[i2][j]=0.f;
    for (int kc=0;kc<4;kc++){
      __syncthreads();
#pragma unroll
      for (int i=0;i<8;i++){
        int idx = t + 256*i;
        int kk = idx & 31, c = idx >> 5;
        int m = m0 + c;
        ams[kk][c] = (m < NPGc) ? Ab[(size_t)m*128 + kc*32 + kk] : 0.f;
      }
      __syncthreads();
#pragma unroll
      for (int kk=0;kk<32;kk++){
        float4 av = *(const float4*)&as[kc*32+kk][r0_];
        float4 bv4 = *(const float4*)&ams[kk][c0];
        float a_[4] = {av.x,av.y,av.z,av.w};
        float b_[4] = {bv4.x,bv4.y,bv4.z,bv4.w};
#pragma unroll
        for (int i2=0;i2<4;i2++)
#pragma unroll
          for (int j=0;j<4;j++)
            acc[i2][j] += a_[i2]*b_[j];
      }
    }
    const int mbase = m0 + c0;
    const bool colok = (mbase < NPGc);   // mbase mult of 4, < 500 => mbase+3 <= 499
#pragma unroll
    for (int i2=0;i2<4;i2++){
      int n = n0 + r0_ + i2;
      bool rowok = colok && (n < NPGc);
      bool fe[4];
      float sj[4];
      if (rowok){
        size_t moff = (size_t)b*250000u + (size_t)n*500u + (size_t)mbase;
        if (isbool){
          uchar4 mk = *(const uchar4*)(mask_u8 + moff);
          fe[0]=mk.x!=0; fe[1]=mk.y!=0; fe[2]=mk.z!=0; fe[3]=mk.w!=0;
        } else {
          int4 mk = *(const int4*)(mask_i32 + moff);
          fe[0]=mk.x!=0; fe[1]=mk.y!=0; fe[2]=mk.z!=0; fe[3]=mk.w!=0;
        }
      } else { fe[0]=fe[1]=fe[2]=fe[3]=false; }
#pragma unroll
      for (int j=0;j<4;j++) sj[j] = fe[j] ? acc[i2][j] : -1e30f;
      // branchless online softmax over the 4 entries
      float tm = fmaxf(fmaxf(sj[0],sj[1]), fmaxf(sj[2],sj[3]));
      float nm = fmaxf(mrun, tm);
      float add = 0.f;
#pragma unroll
      for (int j=0;j<4;j++){
        float e = __expf(sj[j] - nm);
        add += fe[j] ? e : 0.f;
      }
      srun = srun*__expf(mrun - nm) + add;
      mrun = nm;
      // push feasible entries to the block queue
#pragma unroll
      for (int j=0;j<4;j++){
        if (fe[j]){
          int lidx = n*500 + (mbase + j);
          int slot = atomicAdd(&qcnt, 1);
          if (slot < QCAP){
            qs[slot] = acc[i2][j]; qi[slot] = lidx;
          } else {
            // overflow fallback (never hit at ~10% density; keeps worst-case correct)
            float g = gumbel_of(gbase + (unsigned)lidx);
            float val = acc[i2][j] + g;
            if (val > bval || (val == bval && lidx < bidx)){ bval = val; bidx = lidx; bsc = acc[i2][j]; }
          }
        }
      }
    }
    // drain queue with full-lane utilization
    __syncthreads();
    int qn = qcnt; if (qn > QCAP) qn = QCAP;
    for (int i = t; i < qn; i += 256){
      float s = qs[i]; int idx = qi[i];
      float g = gumbel_of(gbase + (unsigned)idx);
      float val = s + g;
      if (val > bval || (val == bval && idx < bidx)){ bval = val; bidx = idx; bsc = s; }
    }
    __syncthreads();
    if (t == 0) qcnt = 0;
    // next mc's staging barrier publishes the reset before any new push
  }
  __syncthreads();
  rm[t]=mrun; rs_[t]=srun; rv[t]=bval; ri[t]=bidx; rsc[t]=bsc;
  __syncthreads();
  for (int offr=128; offr>0; offr>>=1){
    if (t < offr){
      float m1 = rm[t], s1 = rs_[t];
      float m2 = rm[t+offr], s2 = rs_[t+offr];
      float M = fmaxf(m1, m2);
      float S = s1*expf(m1-M) + s2*expf(m2-M);
      rm[t] = M; rs_[t] = S;
      float v2 = rv[t+offr]; int i2_ = ri[t+offr];
      if (v2 > rv[t] || (v2 == rv[t] && i2_ < ri[t])){ rv[t]=v2; ri[t]=i2_; rsc[t]=rsc[t+offr]; }
    }
    __syncthreads();
  }
  if (t == 0){
    float* p = partials + ((size_t)b*8 + tile)*8;
    p[0]=rm[0]; p[1]=rs_[0]; p[2]=rv[0]; p[3]=(float)ri[0]; p[4]=rsc[0];
  }
}

__global__ void finalize_kernel(const float* __restrict__ partials, float* __restrict__ out){
  int b = threadIdx.x;  // 128 threads
  float M = -1e30f, S = 0.f, BV = -FLT_MAX, BS = 0.f;
  int BI = 0x7FFFFFFF;
  for (int tp=0; tp<8; tp++){
    const float* p = partials + ((size_t)b*8 + tp)*8;
    float m = p[0], s = p[1], v = p[2]; int i = (int)p[3]; float sc2 = p[4];
    float nM = fmaxf(M, m);
    S = S*expf(M-nM) + s*expf(m-nM);
    M = nM;
    if (v > BV || (v == BV && i < BI)){ BV = v; BI = i; BS = sc2; }
  }
  out[b]      = (float)BI;
  out[BB + b] = BS - (M + logf(S));
}

// ---------------- host launch ----------------
extern "C" void kernel_launch(void* const* d_in, const int* in_sizes, int n_in,
                              void* d_out, int out_size, void* d_ws, size_t ws_size,
                              hipStream_t stream){
  const float* x        = (const float*)d_in[0];
  const int*   eidx     = (const int*)d_in[1];
  const void*  maskp    = d_in[3];
  const float* gin_W1_0 = (const float*)d_in[4];
  const float* gin_b1_0 = (const float*)d_in[5];
  const float* gin_g_0  = (const float*)d_in[6];
  const float* gin_be_0 = (const float*)d_in[7];
  const float* gin_W2_0 = (const float*)d_in[8];
  const float* gin_b2_0 = (const float*)d_in[9];
  const float* gin_W1   = (const float*)d_in[10];
  const float* gin_b1   = (const float*)d_in[11];
  const float* gin_g    = (const float*)d_in[12];
  const float* gin_be   = (const float*)d_in[13];
  const float* gin_W2   = (const float*)d_in[14];
  const float* gin_b2   = (const float*)d_in[15];
  const float* pol_W1_0 = (const float*)d_in[16];
  const float* pol_b1_0 = (const float*)d_in[17];
  const float* pol_W2_0 = (const float*)d_in[18];
  const float* pol_b2_0 = (const float*)d_in[19];
  const float* pol_W1   = (const float*)d_in[20];
  const float* pol_b1   = (const float*)d_in[21];
  const float* pol_W2   = (const float*)d_in[22];
  const float* pol_b2   = (const float*)d_in[23];
  float* out = (float*)d_out;

  char* p = (char*)d_ws;
  auto carve = [&](size_t bytes) -> void* {
    void* r = (void*)p; p += (bytes + 255) & ~(size_t)255; return r;
  };
  float* hbuf  = (float*)carve((size_t)NN*128*4);
  float* xin   = (float*)carve((size_t)NN*128*4);
  float* pool  = (float*)carve((size_t)NN*128*4);
  float* xin0  = (float*)carve((size_t)NN*3*4);
  float* gpool = (float*)carve((size_t)BB*128*4);
  float* dinv  = (float*)carve((size_t)NN*4);
  float* stats = (float*)carve(256*4);
  float* bnbuf = (float*)carve(256*4);
  float* partials = (float*)carve((size_t)BB*8*8*4);
  int* cnt = (int*)carve((size_t)NN*4);
  int* off = (int*)carve((size_t)(NN+1)*4);
  int* cur = (int*)carve((size_t)NN*4);
  int* csr = (int*)carve((size_t)EE*4);
  int* mflag = (int*)carve(256);

  const int* srcp = eidx;
  const int* dstp = eidx + EE;

  // mask dtype detection (device-side, graph-capture safe)
  maskdet_kernel<<<1, 64, 0, stream>>>((const unsigned*)maskp, mflag);

  // CSR build (self loops handled analytically: deg = cnt+1, self term added in agg)
  hipMemsetAsync(cnt, 0, (size_t)NN*4, stream);
  count_kernel<<<(EE+255)/256, 256, 0, stream>>>(dstp, cnt);
  scan_kernel<<<1, 1024, 0, stream>>>(cnt, off, cur);
  fill_kernel<<<(EE+255)/256, 256, 0, stream>>>(srcp, dstp, cur, csr);
  dinv_kernel<<<(NN+255)/256, 256, 0, stream>>>(cnt, dinv);

  // GIN layer 0
  agg3_kernel<<<(NN+255)/256, 256, 0, stream>>>(x, off, csr, dinv, xin0);
  hipMemsetAsync(stats, 0, 256*4, stream);
  z0_kernel<<<NN/64, 256, 0, stream>>>(xin0, gin_W1_0, gin_b1_0, xin, stats);
  bnfin_kernel<<<1, 128, 0, stream>>>(stats, gin_g_0, gin_be_0, bnbuf);
  linear_kernel<128,false,true,false,false,1><<<NN/128, 256, 0, stream>>>(
      xin, nullptr, gin_W2_0, gin_b2_0, hbuf, bnbuf, bnbuf+128, nullptr, pool);

  // GIN layers 1..3
  for (int l=0; l<3; l++){
    agg128_kernel<<<NN/4, 256, 0, stream>>>(hbuf, off, csr, dinv, xin);
    hipMemsetAsync(stats, 0, 256*4, stream);
    linear_kernel<128,false,false,false,true,0><<<NN/128, 256, 0, stream>>>(
        xin, nullptr, gin_W1 + (size_t)l*16384, gin_b1 + l*128, xin,
        nullptr, nullptr, stats, nullptr);
    bnfin_kernel<<<1, 128, 0, stream>>>(stats, gin_g + l*128, gin_be + l*128, bnbuf);
    linear_kernel<128,false,true,false,false,2><<<NN/128, 256, 0, stream>>>(
        xin, nullptr, gin_W2 + (size_t)l*16384, gin_b2 + l*128, hbuf,
        bnbuf, bnbuf+128, nullptr, pool);
  }

  // policy MLP
  gpool_kernel<<<BB, 128, 0, stream>>>(pool, gpool);
  linear_kernel<256,true,false,true,false,0><<<NN/128, 256, 0, stream>>>(
      pool, gpool, pol_W1_0, pol_b1_0, hbuf, nullptr, nullptr, nullptr, nullptr);
  linear_kernel<128,false,false,false,false,0><<<NN/128, 256, 0, stream>>>(
      hbuf, nullptr, pol_W2_0, pol_b2_0, xin, nullptr, nullptr, nullptr, nullptr);
  linear_kernel<128,false,false,true,false,0><<<NN/128, 256, 0, stream>>>(
      xin, nullptr, pol_W1, pol_b1, hbuf, nullptr, nullptr, nullptr, nullptr);
  linear_kernel<128,false,false,false,false,0><<<NN/128, 256, 0, stream>>>(
      hbuf, nullptr, pol_W2, pol_b2, xin, nullptr, nullptr, nullptr, nullptr);
  linear_kernel<128,false,false,true,false,0><<<NN/128, 256, 0, stream>>>(
      xin, nullptr, pol_W1 + 16384, pol_b1 + 128, hbuf, nullptr, nullptr, nullptr, nullptr);
  linear_kernel<128,false,false,false,false,0><<<NN/128, 256, 0, stream>>>(
      hbuf, nullptr, pol_W2 + 16384, pol_b2 + 128, xin, nullptr, nullptr, nullptr, nullptr);

  // scores + sampling
  dim3 sg(8, BB);
  scores_kernel<<<sg, 256, 0, stream>>>(xin, (const unsigned char*)maskp,
                                        (const int*)maskp, mflag, partials);
  finalize_kernel<<<1, BB, 0, stream>>>(partials, out);
}

// Round 6
// 1560.918 us; speedup vs baseline: 1.6271x; 1.6271x over previous
//
#include <hip/hip_runtime.h>
#include <float.h>

#define NN 64000
#define BB 128
#define NPGc 500
#define EE 512000

// ---------------- threefry2x32, JAX partitionable path, key = (0,42) ----------------
__device__ __forceinline__ unsigned rotl32(unsigned x, unsigned r){ return (x<<r)|(x>>(32u-r)); }

__device__ __forceinline__ unsigned threefry_bits(unsigned idx){
  unsigned x0 = 0u, x1 = idx;
  const unsigned ks0 = 0u, ks1 = 42u, ks2 = 0u ^ 42u ^ 0x1BD11BDAu;
  x0 += ks0; x1 += ks1;
#define RND(r) { x0 += x1; x1 = rotl32(x1, r); x1 ^= x0; }
  RND(13u) RND(15u) RND(26u) RND(6u)   x0 += ks1; x1 += ks2 + 1u;
  RND(17u) RND(29u) RND(16u) RND(24u)  x0 += ks2; x1 += ks0 + 2u;
  RND(13u) RND(15u) RND(26u) RND(6u)   x0 += ks0; x1 += ks1 + 3u;
  RND(17u) RND(29u) RND(16u) RND(24u)  x0 += ks1; x1 += ks2 + 4u;
  RND(13u) RND(15u) RND(26u) RND(6u)   x0 += ks2; x1 += ks0 + 5u;
#undef RND
  return x0 ^ x1;
}

__device__ __forceinline__ float gumbel_of(unsigned idx){
  unsigned bits = threefry_bits(idx);
  float f = __uint_as_float((bits >> 9) | 0x3f800000u) - 1.0f;
  const float TINY = 1.17549435e-38f;
  float u = fmaxf(TINY, f + TINY);
  return -logf(-logf(u));   // precise logf: argmax must match ref bit-wise
}

__device__ __forceinline__ float fast_tanh(float x){
  return 1.0f - 2.0f/(__expf(2.0f*x) + 1.0f);
}

// ---------------- mask dtype detection ----------------
__global__ void maskdet_kernel(const unsigned* __restrict__ m, int* __restrict__ flag){
  if (threadIdx.x == 0){
    int isbool = 0;
    for (int i=0;i<256;i++){ if (m[i] > 1u){ isbool = 1; break; } }
    *flag = isbool;
  }
}

// ---------------- CSR build ----------------
__global__ void count_kernel(const int* __restrict__ dst, int* __restrict__ cnt){
  int e = blockIdx.x*256 + threadIdx.x;
  if (e < EE) atomicAdd(&cnt[dst[e]], 1);
}

__global__ __launch_bounds__(1024)
void scan_kernel(const int* __restrict__ cnt, int* __restrict__ off, int* __restrict__ cur){
  __shared__ int part[1024];
  int tid = threadIdx.x;
  const int chunk = 63;
  int base = tid*chunk;
  int sum = 0;
  for (int i=0;i<chunk;i++){ int n = base+i; if (n < NN) sum += cnt[n]; }
  part[tid] = sum;
  __syncthreads();
  for (int d=1; d<1024; d<<=1){
    int v = (tid >= d) ? part[tid-d] : 0;
    __syncthreads();
    part[tid] += v;
    __syncthreads();
  }
  int run = part[tid] - sum;
  for (int i=0;i<chunk;i++){
    int n = base+i;
    if (n < NN){ off[n] = run; cur[n] = run; run += cnt[n]; }
  }
  if (tid == 1023) off[NN] = run;
}

__global__ void fill_kernel(const int* __restrict__ src, const int* __restrict__ dst,
                            int* __restrict__ cur, int* __restrict__ csr){
  int e = blockIdx.x*256 + threadIdx.x;
  if (e < EE){
    int d = dst[e];
    int p = atomicAdd(&cur[d], 1);
    csr[p] = src[e];
  }
}

__global__ void dinv_kernel(const int* __restrict__ cnt, float* __restrict__ dinv){
  int n = blockIdx.x*256 + threadIdx.x;
  if (n < NN) dinv[n] = 1.0f/(float)(cnt[n]+1);
}

// ---------------- aggregation ----------------
__global__ void agg3_kernel(const float* __restrict__ x, const int* __restrict__ off,
                            const int* __restrict__ csr, const float* __restrict__ dinv,
                            float* __restrict__ xin0){
  int n = blockIdx.x*256 + threadIdx.x;
  if (n >= NN) return;
  float a0 = x[n*3], a1 = x[n*3+1], a2 = x[n*3+2];
  float s0 = a0, s1 = a1, s2 = a2;
  int e1 = off[n+1];
  for (int e = off[n]; e < e1; ++e){
    int s = csr[e];
    s0 += x[s*3]; s1 += x[s*3+1]; s2 += x[s*3+2];
  }
  float di = dinv[n];
  xin0[n*3]   = a0 + s0*di;
  xin0[n*3+1] = a1 + s1*di;
  xin0[n*3+2] = a2 + s2*di;
}

__global__ __launch_bounds__(256)
void agg128_kernel(const float* __restrict__ h, const int* __restrict__ off,
                   const int* __restrict__ csr, const float* __restrict__ dinv,
                   float* __restrict__ xin){
  int w = (blockIdx.x*256 + threadIdx.x) >> 6;
  int lane = threadIdx.x & 63;
  if (w >= NN) return;
  const float* hn = h + (size_t)w*128;
  float a0 = hn[lane], a1 = hn[lane+64];
  float s0 = a0, s1 = a1;              // self loop included in agg sum
  int e0 = off[w], e1 = off[w+1];
  for (int e = e0; e < e1; ++e){
    int s = csr[e];
    const float* hs = h + (size_t)s*128;
    s0 += hs[lane]; s1 += hs[lane+64];
  }
  float di = dinv[w];
  xin[(size_t)w*128 + lane]      = a0 + s0*di;
  xin[(size_t)w*128 + lane + 64] = a1 + s1*di;
}

// ---------------- layer-0 z (K=3) with BN stats ----------------
__global__ __launch_bounds__(256)
void z0_kernel(const float* __restrict__ xin0, const float* __restrict__ W,
               const float* __restrict__ bias, float* __restrict__ z,
               float* __restrict__ stats){
  __shared__ float xr[192];
  __shared__ float ssum[128], ssq[128];
  int t = threadIdx.x;
  int row0 = blockIdx.x*64;
  if (t < 192) xr[t] = xin0[(size_t)row0*3 + t];
  if (t < 128){ ssum[t]=0.f; ssq[t]=0.f; }
  int f = t & 127, rg = t >> 7;
  float w0 = W[f], w1 = W[128+f], w2 = W[256+f], bb = bias[f];
  __syncthreads();
  float s = 0.f, q = 0.f;
  for (int i=0;i<32;i++){
    int r = rg*32 + i;
    float y = bb + xr[r*3]*w0 + xr[r*3+1]*w1 + xr[r*3+2]*w2;
    z[(size_t)(row0+r)*128 + f] = y;
    s += y; q += y*y;
  }
  atomicAdd(&ssum[f], s); atomicAdd(&ssq[f], q);
  __syncthreads();
  if (t < 128){ atomicAdd(&stats[t], ssum[t]); atomicAdd(&stats[128+t], ssq[t]); }
}

__global__ void bnfin_kernel(const float* __restrict__ stats, const float* __restrict__ g,
                             const float* __restrict__ be, float* __restrict__ bnbuf){
  int f = threadIdx.x;
  float mu  = stats[f]     * (1.0f/NN);
  float var = stats[128+f] * (1.0f/NN) - mu*mu;
  float rsv = rsqrtf(var + 1e-5f);
  float sc  = g[f]*rsv;
  bnbuf[f]      = sc;
  bnbuf[128+f]  = be[f] - mu*sc;
}

// ---------------- fp32 linear: 128 rows x 128 out per block, 8x8 micro-tile ----------------
// __launch_bounds__(256, 2): allow up to 256 VGPRs — (256,4) capped at 128 and
// spilled the 64-reg accumulator to scratch (round-5 regression, ~4x per-dispatch).
// POOLM: 0 none, 1 pool = y, 2 pool += y
template<int K, bool CATF, bool BNF, bool TANHF, bool STATSF, int POOLM>
__global__ __launch_bounds__(256, 2)
void linear_kernel(const float* X, const float* __restrict__ X2,
                   const float* __restrict__ W, const float* __restrict__ bias,
                   float* Y,
                   const float* __restrict__ bnsc, const float* __restrict__ bnsh,
                   float* __restrict__ stats, float* __restrict__ pool){
  __shared__ __align__(16) float xs[32][132];
  __shared__ __align__(16) float ws[32][132];
  __shared__ float ssum[128], ssq[128];
  const int t = threadIdx.x;
  const int row0 = blockIdx.x*128;
  const int cg = t & 15, rg = t >> 4;
  const int c0 = cg*8, r0 = rg*8;
  float acc[8][8];
#pragma unroll
  for (int r=0;r<8;r++)
#pragma unroll
    for (int c=0;c<8;c++) acc[r][c]=0.f;
  if (STATSF && t < 128){ ssum[t]=0.f; ssq[t]=0.f; }

  for (int kc=0; kc<K; kc+=32){
    __syncthreads();
#pragma unroll
    for (int i=0;i<16;i++){
      int idx = t + 256*i;
      int k = idx & 31, r = idx >> 5;
      int gk = kc + k;
      int n = row0 + r;
      float v;
      if (CATF){
        v = (gk < 128) ? X[(size_t)n*128 + gk] : X2[(size_t)(n/NPGc)*128 + (gk-128)];
      } else {
        v = X[(size_t)n*K + gk];
      }
      if (BNF) v = fmaxf(0.f, v*bnsc[gk] + bnsh[gk]);
      xs[k][r] = v;
    }
#pragma unroll
    for (int i=0;i<16;i++){
      int idx = t + 256*i;
      int c = idx & 127, k = idx >> 7;
      ws[k][c] = W[(size_t)(kc+k)*128 + c];
    }
    __syncthreads();
#pragma unroll
    for (int k=0;k<32;k++){
      float4 xa = *(const float4*)&xs[k][r0];
      float4 xb = *(const float4*)&xs[k][r0+4];
      float4 wa = *(const float4*)&ws[k][c0];
      float4 wb = *(const float4*)&ws[k][c0+4];
      float xv[8] = {xa.x,xa.y,xa.z,xa.w,xb.x,xb.y,xb.z,xb.w};
      float wv[8] = {wa.x,wa.y,wa.z,wa.w,wb.x,wb.y,wb.z,wb.w};
#pragma unroll
      for (int r=0;r<8;r++)
#pragma unroll
        for (int c=0;c<8;c++)
          acc[r][c] += xv[r]*wv[c];
    }
  }
  float4 ba = *(const float4*)(bias + c0);
  float4 bb2 = *(const float4*)(bias + c0 + 4);
  float bv[8] = {ba.x,ba.y,ba.z,ba.w,bb2.x,bb2.y,bb2.z,bb2.w};
  float sc8[8], sq8[8];
#pragma unroll
  for (int c=0;c<8;c++){ sc8[c]=0.f; sq8[c]=0.f; }
#pragma unroll
  for (int r=0;r<8;r++){
    int n = row0 + r0 + r;
    float y[8];
#pragma unroll
    for (int c=0;c<8;c++){
      float v = acc[r][c] + bv[c];
      if (TANHF) v = fast_tanh(v);
      y[c] = v;
    }
    float4 y0; y0.x=y[0]; y0.y=y[1]; y0.z=y[2]; y0.w=y[3];
    float4 y1; y1.x=y[4]; y1.y=y[5]; y1.z=y[6]; y1.w=y[7];
    *(float4*)(Y + (size_t)n*128 + c0)     = y0;
    *(float4*)(Y + (size_t)n*128 + c0 + 4) = y1;
    if (POOLM == 1){
      *(float4*)(pool + (size_t)n*128 + c0)     = y0;
      *(float4*)(pool + (size_t)n*128 + c0 + 4) = y1;
    } else if (POOLM == 2){
      float4 p0 = *(const float4*)(pool + (size_t)n*128 + c0);
      float4 p1 = *(const float4*)(pool + (size_t)n*128 + c0 + 4);
      p0.x+=y[0]; p0.y+=y[1]; p0.z+=y[2]; p0.w+=y[3];
      p1.x+=y[4]; p1.y+=y[5]; p1.z+=y[6]; p1.w+=y[7];
      *(float4*)(pool + (size_t)n*128 + c0)     = p0;
      *(float4*)(pool + (size_t)n*128 + c0 + 4) = p1;
    }
    if (STATSF){
#pragma unroll
      for (int c=0;c<8;c++){ sc8[c]+=y[c]; sq8[c]+=y[c]*y[c]; }
    }
  }
  if (STATSF){
#pragma unroll
    for (int c=0;c<8;c++){
      atomicAdd(&ssum[c0+c], sc8[c]);
      atomicAdd(&ssq[c0+c],  sq8[c]);
    }
    __syncthreads();
    if (t < 128){
      atomicAdd(&stats[t],     ssum[t]);
      atomicAdd(&stats[128+t], ssq[t]);
    }
  }
}

// ---------------- graph pool (mean of node_pool per graph) ----------------
__global__ void gpool_kernel(const float* __restrict__ pool, float* __restrict__ gpool){
  int b = blockIdx.x, f = threadIdx.x;
  const float* p = pool + (size_t)b*NPGc*128 + f;
  float s = 0.f;
  for (int i=0;i<NPGc;i++) s += p[(size_t)i*128];
  gpool[(size_t)b*128 + f] = s * (1.0f/NPGc);
}

// ---------------- scores + mask + gumbel (queue-compacted) + online softmax + argmax --------
#define QCAP 1024

__global__ __launch_bounds__(256)
void scores_kernel(const float* __restrict__ A, const unsigned char* __restrict__ mask_u8,
                   const int* __restrict__ mask_i32, const int* __restrict__ mflag,
                   float* __restrict__ partials){
  __shared__ __align__(16) float as[128][68];
  __shared__ __align__(16) float ams[32][68];
  __shared__ float qs[QCAP];
  __shared__ int   qi[QCAP];
  __shared__ int   qcnt;
  float* rm  = qs;
  float* rs_ = qs + 256;
  float* rv  = qs + 512;
  float* rsc = qs + 768;
  int*   ri  = qi;
  const int t = threadIdx.x;
  const int b = blockIdx.y, tile = blockIdx.x;
  const int n0 = tile*64;
  const int cgc = t & 15, rgc = t >> 4;
  const int r0_ = rgc*4, c0 = cgc*4;
  const float* Ab = A + (size_t)b*NPGc*128;
  const unsigned gbase = (unsigned)b*250000u;
  const int isbool = *mflag;
  if (t == 0) qcnt = 0;

#pragma unroll
  for (int i=0;i<32;i++){
    int idx = t + 256*i;
    int k = idx & 127, r = idx >> 7;
    int n = n0 + r;
    as[k][r] = (n < NPGc) ? Ab[(size_t)n*128 + k] : 0.f;
  }

  float mrun = -1e30f, srun = 0.f, bval = -FLT_MAX, bsc = 0.f;
  int bidx = 0x7FFFFFFF;

  for (int mc=0; mc<8; mc++){
    int m0 = mc*64;
    float acc[4][4];
#pragma unroll
    for (int i2=0;i2<4;i2++)
#pragma unroll
      for (int j=0;j<4;j++) acc[i2][j]=0.f;
    for (int kc=0;kc<4;kc++){
      __syncthreads();
#pragma unroll
      for (int i=0;i<8;i++){
        int idx = t + 256*i;
        int kk = idx & 31, c = idx >> 5;
        int m = m0 + c;
        ams[kk][c] = (m < NPGc) ? Ab[(size_t)m*128 + kc*32 + kk] : 0.f;
      }
      __syncthreads();
#pragma unroll
      for (int kk=0;kk<32;kk++){
        float4 av = *(const float4*)&as[kc*32+kk][r0_];
        float4 bv4 = *(const float4*)&ams[kk][c0];
        float a_[4] = {av.x,av.y,av.z,av.w};
        float b_[4] = {bv4.x,bv4.y,bv4.z,bv4.w};
#pragma unroll
        for (int i2=0;i2<4;i2++)
#pragma unroll
          for (int j=0;j<4;j++)
            acc[i2][j] += a_[i2]*b_[j];
      }
    }
    const int mbase = m0 + c0;
    const bool colok = (mbase < NPGc);
#pragma unroll
    for (int i2=0;i2<4;i2++){
      int n = n0 + r0_ + i2;
      bool rowok = colok && (n < NPGc);
      bool fe[4];
      float sj[4];
      if (rowok){
        size_t moff = (size_t)b*250000u + (size_t)n*500u + (size_t)mbase;
        if (isbool){
          uchar4 mk = *(const uchar4*)(mask_u8 + moff);
          fe[0]=mk.x!=0; fe[1]=mk.y!=0; fe[2]=mk.z!=0; fe[3]=mk.w!=0;
        } else {
          int4 mk = *(const int4*)(mask_i32 + moff);
          fe[0]=mk.x!=0; fe[1]=mk.y!=0; fe[2]=mk.z!=0; fe[3]=mk.w!=0;
        }
      } else { fe[0]=fe[1]=fe[2]=fe[3]=false; }
#pragma unroll
      for (int j=0;j<4;j++) sj[j] = fe[j] ? acc[i2][j] : -1e30f;
      float tm = fmaxf(fmaxf(sj[0],sj[1]), fmaxf(sj[2],sj[3]));
      float nm = fmaxf(mrun, tm);
      float add = 0.f;
#pragma unroll
      for (int j=0;j<4;j++){
        float e = __expf(sj[j] - nm);
        add += fe[j] ? e : 0.f;
      }
      srun = srun*__expf(mrun - nm) + add;
      mrun = nm;
#pragma unroll
      for (int j=0;j<4;j++){
        if (fe[j]){
          int lidx = n*500 + (mbase + j);
          int slot = atomicAdd(&qcnt, 1);
          if (slot < QCAP){
            qs[slot] = acc[i2][j]; qi[slot] = lidx;
          } else {
            float g = gumbel_of(gbase + (unsigned)lidx);
            float val = acc[i2][j] + g;
            if (val > bval || (val == bval && lidx < bidx)){ bval = val; bidx = lidx; bsc = acc[i2][j]; }
          }
        }
      }
    }
    __syncthreads();
    int qn = qcnt; if (qn > QCAP) qn = QCAP;
    for (int i = t; i < qn; i += 256){
      float s = qs[i]; int idx = qi[i];
      float g = gumbel_of(gbase + (unsigned)idx);
      float val = s + g;
      if (val > bval || (val == bval && idx < bidx)){ bval = val; bidx = idx; bsc = s; }
    }
    __syncthreads();
    if (t == 0) qcnt = 0;
  }
  __syncthreads();
  rm[t]=mrun; rs_[t]=srun; rv[t]=bval; ri[t]=bidx; rsc[t]=bsc;
  __syncthreads();
  for (int offr=128; offr>0; offr>>=1){
    if (t < offr){
      float m1 = rm[t], s1 = rs_[t];
      float m2 = rm[t+offr], s2 = rs_[t+offr];
      float M = fmaxf(m1, m2);
      float S = s1*expf(m1-M) + s2*expf(m2-M);
      rm[t] = M; rs_[t] = S;
      float v2 = rv[t+offr]; int i2_ = ri[t+offr];
      if (v2 > rv[t] || (v2 == rv[t] && i2_ < ri[t])){ rv[t]=v2; ri[t]=i2_; rsc[t]=rsc[t+offr]; }
    }
    __syncthreads();
  }
  if (t == 0){
    float* p = partials + ((size_t)b*8 + tile)*8;
    p[0]=rm[0]; p[1]=rs_[0]; p[2]=rv[0]; p[3]=(float)ri[0]; p[4]=rsc[0];
  }
}

__global__ void finalize_kernel(const float* __restrict__ partials, float* __restrict__ out){
  int b = threadIdx.x;
  float M = -1e30f, S = 0.f, BV = -FLT_MAX, BS = 0.f;
  int BI = 0x7FFFFFFF;
  for (int tp=0; tp<8; tp++){
    const float* p = partials + ((size_t)b*8 + tp)*8;
    float m = p[0], s = p[1], v = p[2]; int i = (int)p[3]; float sc2 = p[4];
    float nM = fmaxf(M, m);
    S = S*expf(M-nM) + s*expf(m-nM);
    M = nM;
    if (v > BV || (v == BV && i < BI)){ BV = v; BI = i; BS = sc2; }
  }
  out[b]      = (float)BI;
  out[BB + b] = BS - (M + logf(S));
}

// ---------------- host launch ----------------
extern "C" void kernel_launch(void* const* d_in, const int* in_sizes, int n_in,
                              void* d_out, int out_size, void* d_ws, size_t ws_size,
                              hipStream_t stream){
  const float* x        = (const float*)d_in[0];
  const int*   eidx     = (const int*)d_in[1];
  const void*  maskp    = d_in[3];
  const float* gin_W1_0 = (const float*)d_in[4];
  const float* gin_b1_0 = (const float*)d_in[5];
  const float* gin_g_0  = (const float*)d_in[6];
  const float* gin_be_0 = (const float*)d_in[7];
  const float* gin_W2_0 = (const float*)d_in[8];
  const float* gin_b2_0 = (const float*)d_in[9];
  const float* gin_W1   = (const float*)d_in[10];
  const float* gin_b1   = (const float*)d_in[11];
  const float* gin_g    = (const float*)d_in[12];
  const float* gin_be   = (const float*)d_in[13];
  const float* gin_W2   = (const float*)d_in[14];
  const float* gin_b2   = (const float*)d_in[15];
  const float* pol_W1_0 = (const float*)d_in[16];
  const float* pol_b1_0 = (const float*)d_in[17];
  const float* pol_W2_0 = (const float*)d_in[18];
  const float* pol_b2_0 = (const float*)d_in[19];
  const float* pol_W1   = (const float*)d_in[20];
  const float* pol_b1   = (const float*)d_in[21];
  const float* pol_W2   = (const float*)d_in[22];
  const float* pol_b2   = (const float*)d_in[23];
  float* out = (float*)d_out;

  char* p = (char*)d_ws;
  auto carve = [&](size_t bytes) -> void* {
    void* r = (void*)p; p += (bytes + 255) & ~(size_t)255; return r;
  };
  float* hbuf  = (float*)carve((size_t)NN*128*4);
  float* xin   = (float*)carve((size_t)NN*128*4);
  float* pool  = (float*)carve((size_t)NN*128*4);
  float* xin0  = (float*)carve((size_t)NN*3*4);
  float* gpool = (float*)carve((size_t)BB*128*4);
  float* dinv  = (float*)carve((size_t)NN*4);
  float* stats = (float*)carve(256*4);
  float* bnbuf = (float*)carve(256*4);
  float* partials = (float*)carve((size_t)BB*8*8*4);
  int* cnt = (int*)carve((size_t)NN*4);
  int* off = (int*)carve((size_t)(NN+1)*4);
  int* cur = (int*)carve((size_t)NN*4);
  int* csr = (int*)carve((size_t)EE*4);
  int* mflag = (int*)carve(256);

  const int* srcp = eidx;
  const int* dstp = eidx + EE;

  maskdet_kernel<<<1, 64, 0, stream>>>((const unsigned*)maskp, mflag);

  hipMemsetAsync(cnt, 0, (size_t)NN*4, stream);
  count_kernel<<<(EE+255)/256, 256, 0, stream>>>(dstp, cnt);
  scan_kernel<<<1, 1024, 0, stream>>>(cnt, off, cur);
  fill_kernel<<<(EE+255)/256, 256, 0, stream>>>(srcp, dstp, cur, csr);
  dinv_kernel<<<(NN+255)/256, 256, 0, stream>>>(cnt, dinv);

  // GIN layer 0
  agg3_kernel<<<(NN+255)/256, 256, 0, stream>>>(x, off, csr, dinv, xin0);
  hipMemsetAsync(stats, 0, 256*4, stream);
  z0_kernel<<<NN/64, 256, 0, stream>>>(xin0, gin_W1_0, gin_b1_0, xin, stats);
  bnfin_kernel<<<1, 128, 0, stream>>>(stats, gin_g_0, gin_be_0, bnbuf);
  linear_kernel<128,false,true,false,false,1><<<NN/128, 256, 0, stream>>>(
      xin, nullptr, gin_W2_0, gin_b2_0, hbuf, bnbuf, bnbuf+128, nullptr, pool);

  // GIN layers 1..3
  for (int l=0; l<3; l++){
    agg128_kernel<<<NN/4, 256, 0, stream>>>(hbuf, off, csr, dinv, xin);
    hipMemsetAsync(stats, 0, 256*4, stream);
    linear_kernel<128,false,false,false,true,0><<<NN/128, 256, 0, stream>>>(
        xin, nullptr, gin_W1 + (size_t)l*16384, gin_b1 + l*128, xin,
        nullptr, nullptr, stats, nullptr);
    bnfin_kernel<<<1, 128, 0, stream>>>(stats, gin_g + l*128, gin_be + l*128, bnbuf);
    linear_kernel<128,false,true,false,false,2><<<NN/128, 256, 0, stream>>>(
        xin, nullptr, gin_W2 + (size_t)l*16384, gin_b2 + l*128, hbuf,
        bnbuf, bnbuf+128, nullptr, pool);
  }

  // policy MLP
  gpool_kernel<<<BB, 128, 0, stream>>>(pool, gpool);
  linear_kernel<256,true,false,true,false,0><<<NN/128, 256, 0, stream>>>(
      pool, gpool, pol_W1_0, pol_b1_0, hbuf, nullptr, nullptr, nullptr, nullptr);
  linear_kernel<128,false,false,false,false,0><<<NN/128, 256, 0, stream>>>(
      hbuf, nullptr, pol_W2_0, pol_b2_0, xin, nullptr, nullptr, nullptr, nullptr);
  linear_kernel<128,false,false,true,false,0><<<NN/128, 256, 0, stream>>>(
      xin, nullptr, pol_W1, pol_b1, hbuf, nullptr, nullptr, nullptr, nullptr);
  linear_kernel<128,false,false,false,false,0><<<NN/128, 256, 0, stream>>>(
      hbuf, nullptr, pol_W2, pol_b2, xin, nullptr, nullptr, nullptr, nullptr);
  linear_kernel<128,false,false,true,false,0><<<NN/128, 256, 0, stream>>>(
      xin, nullptr, pol_W1 + 16384, pol_b1 + 128, hbuf, nullptr, nullptr, nullptr, nullptr);
  linear_kernel<128,false,false,false,false,0><<<NN/128, 256, 0, stream>>>(
      hbuf, nullptr, pol_W2 + 16384, pol_b2 + 128, xin, nullptr, nullptr, nullptr, nullptr);

  // scores + sampling
  dim3 sg(8, BB);
  scores_kernel<<<sg, 256, 0, stream>>>(xin, (const unsigned char*)maskp,
                                        (const int*)maskp, mflag, partials);
  finalize_kernel<<<1, BB, 0, stream>>>(partials, out);
}

// Round 7
// 1536.625 us; speedup vs baseline: 1.6528x; 1.0158x over previous
//
#include <hip/hip_runtime.h>
#include <float.h>

#define NN 64000
#define BB 128
#define NPGc 500
#define EE 512000

// ---------------- threefry2x32, JAX partitionable path, key = (0,42) ----------------
__device__ __forceinline__ unsigned rotl32(unsigned x, unsigned r){ return (x<<r)|(x>>(32u-r)); }

__device__ __forceinline__ unsigned threefry_bits(unsigned idx){
  unsigned x0 = 0u, x1 = idx;
  const unsigned ks0 = 0u, ks1 = 42u, ks2 = 0u ^ 42u ^ 0x1BD11BDAu;
  x0 += ks0; x1 += ks1;
#define RND(r) { x0 += x1; x1 = rotl32(x1, r); x1 ^= x0; }
  RND(13u) RND(15u) RND(26u) RND(6u)   x0 += ks1; x1 += ks2 + 1u;
  RND(17u) RND(29u) RND(16u) RND(24u)  x0 += ks2; x1 += ks0 + 2u;
  RND(13u) RND(15u) RND(26u) RND(6u)   x0 += ks0; x1 += ks1 + 3u;
  RND(17u) RND(29u) RND(16u) RND(24u)  x0 += ks1; x1 += ks2 + 4u;
  RND(13u) RND(15u) RND(26u) RND(6u)   x0 += ks2; x1 += ks0 + 5u;
#undef RND
  return x0 ^ x1;
}

__device__ __forceinline__ float gumbel_of(unsigned idx){
  unsigned bits = threefry_bits(idx);
  float f = __uint_as_float((bits >> 9) | 0x3f800000u) - 1.0f;
  const float TINY = 1.17549435e-38f;
  float u = fmaxf(TINY, f + TINY);
  return -logf(-logf(u));   // precise logf: argmax must match ref bit-wise
}

__device__ __forceinline__ float fast_tanh(float x){
  return 1.0f - 2.0f/(__expf(2.0f*x) + 1.0f);
}

// ---------------- mask dtype detection ----------------
__global__ void maskdet_kernel(const unsigned* __restrict__ m, int* __restrict__ flag){
  if (threadIdx.x == 0){
    int isbool = 0;
    for (int i=0;i<256;i++){ if (m[i] > 1u){ isbool = 1; break; } }
    *flag = isbool;
  }
}

// ---------------- transposed uchar mask: mt8[b][n][m] = mask[b][m][n] ----------------
__global__ __launch_bounds__(256)
void maskprep_kernel(const unsigned char* __restrict__ mu8src, const int* __restrict__ mi32src,
                     const int* __restrict__ mflag, unsigned char* __restrict__ mt8){
  __shared__ unsigned char tile[64][65];
  const int b = blockIdx.y;
  const int rt = blockIdx.x >> 3, ct = blockIdx.x & 7;
  const int t = threadIdx.x;
  const int lane = t & 63, rr = t >> 6;   // rr in 0..3
  const int isbool = *mflag;
#pragma unroll
  for (int p=0;p<16;p++){
    int row = rt*64 + p*4 + rr;
    int col = ct*64 + lane;
    unsigned char v = 0;
    if (row < NPGc && col < NPGc){
      size_t off = (size_t)b*250000 + (size_t)row*500 + col;
      v = isbool ? mu8src[off] : (unsigned char)(mi32src[off] != 0);
    }
    tile[p*4+rr][lane] = v;
  }
  __syncthreads();
#pragma unroll
  for (int p=0;p<16;p++){
    int orow = ct*64 + p*4 + rr;
    int ocol = rt*64 + lane;
    if (orow < NPGc && ocol < NPGc){
      size_t off = (size_t)b*250000 + (size_t)orow*500 + ocol;
      mt8[off] = tile[lane][p*4+rr];
    }
  }
}

// ---------------- CSR build ----------------
__global__ void count_kernel(const int* __restrict__ dst, int* __restrict__ cnt){
  int e = blockIdx.x*256 + threadIdx.x;
  if (e < EE) atomicAdd(&cnt[dst[e]], 1);
}

__global__ __launch_bounds__(1024)
void scan_kernel(const int* __restrict__ cnt, int* __restrict__ off, int* __restrict__ cur){
  __shared__ int part[1024];
  int tid = threadIdx.x;
  const int chunk = 63;
  int base = tid*chunk;
  int sum = 0;
  for (int i=0;i<chunk;i++){ int n = base+i; if (n < NN) sum += cnt[n]; }
  part[tid] = sum;
  __syncthreads();
  for (int d=1; d<1024; d<<=1){
    int v = (tid >= d) ? part[tid-d] : 0;
    __syncthreads();
    part[tid] += v;
    __syncthreads();
  }
  int run = part[tid] - sum;
  for (int i=0;i<chunk;i++){
    int n = base+i;
    if (n < NN){ off[n] = run; cur[n] = run; run += cnt[n]; }
  }
  if (tid == 1023) off[NN] = run;
}

__global__ void fill_kernel(const int* __restrict__ src, const int* __restrict__ dst,
                            int* __restrict__ cur, int* __restrict__ csr){
  int e = blockIdx.x*256 + threadIdx.x;
  if (e < EE){
    int d = dst[e];
    int p = atomicAdd(&cur[d], 1);
    csr[p] = src[e];
  }
}

__global__ void dinv_kernel(const int* __restrict__ cnt, float* __restrict__ dinv){
  int n = blockIdx.x*256 + threadIdx.x;
  if (n < NN) dinv[n] = 1.0f/(float)(cnt[n]+1);
}

// ---------------- aggregation ----------------
__global__ void agg3_kernel(const float* __restrict__ x, const int* __restrict__ off,
                            const int* __restrict__ csr, const float* __restrict__ dinv,
                            float* __restrict__ xin0){
  int n = blockIdx.x*256 + threadIdx.x;
  if (n >= NN) return;
  float a0 = x[n*3], a1 = x[n*3+1], a2 = x[n*3+2];
  float s0 = a0, s1 = a1, s2 = a2;
  int e1 = off[n+1];
  for (int e = off[n]; e < e1; ++e){
    int s = csr[e];
    s0 += x[s*3]; s1 += x[s*3+1]; s2 += x[s*3+2];
  }
  float di = dinv[n];
  xin0[n*3]   = a0 + s0*di;
  xin0[n*3+1] = a1 + s1*di;
  xin0[n*3+2] = a2 + s2*di;
}

__global__ __launch_bounds__(256)
void agg128_kernel(const float* __restrict__ h, const int* __restrict__ off,
                   const int* __restrict__ csr, const float* __restrict__ dinv,
                   float* __restrict__ xin){
  int w = (blockIdx.x*256 + threadIdx.x) >> 6;
  int lane = threadIdx.x & 63;
  if (w >= NN) return;
  const float* hn = h + (size_t)w*128;
  float a0 = hn[lane], a1 = hn[lane+64];
  float s0 = a0, s1 = a1;              // self loop included in agg sum
  int e0 = off[w], e1 = off[w+1];
  for (int e = e0; e < e1; ++e){
    int s = csr[e];
    const float* hs = h + (size_t)s*128;
    s0 += hs[lane]; s1 += hs[lane+64];
  }
  float di = dinv[w];
  xin[(size_t)w*128 + lane]      = a0 + s0*di;
  xin[(size_t)w*128 + lane + 64] = a1 + s1*di;
}

// ---------------- layer-0 z (K=3) with BN stats ----------------
__global__ __launch_bounds__(256)
void z0_kernel(const float* __restrict__ xin0, const float* __restrict__ W,
               const float* __restrict__ bias, float* __restrict__ z,
               float* __restrict__ stats){
  __shared__ float xr[192];
  __shared__ float ssum[128], ssq[128];
  int t = threadIdx.x;
  int row0 = blockIdx.x*64;
  if (t < 192) xr[t] = xin0[(size_t)row0*3 + t];
  if (t < 128){ ssum[t]=0.f; ssq[t]=0.f; }
  int f = t & 127, rg = t >> 7;
  float w0 = W[f], w1 = W[128+f], w2 = W[256+f], bb = bias[f];
  __syncthreads();
  float s = 0.f, q = 0.f;
  for (int i=0;i<32;i++){
    int r = rg*32 + i;
    float y = bb + xr[r*3]*w0 + xr[r*3+1]*w1 + xr[r*3+2]*w2;
    z[(size_t)(row0+r)*128 + f] = y;
    s += y; q += y*y;
  }
  atomicAdd(&ssum[f], s); atomicAdd(&ssq[f], q);
  __syncthreads();
  if (t < 128){ atomicAdd(&stats[t], ssum[t]); atomicAdd(&stats[128+t], ssq[t]); }
}

__global__ void bnfin_kernel(const float* __restrict__ stats, const float* __restrict__ g,
                             const float* __restrict__ be, float* __restrict__ bnbuf){
  int f = threadIdx.x;
  float mu  = stats[f]     * (1.0f/NN);
  float var = stats[128+f] * (1.0f/NN) - mu*mu;
  float rsv = rsqrtf(var + 1e-5f);
  float sc  = g[f]*rsv;
  bnbuf[f]      = sc;
  bnbuf[128+f]  = be[f] - mu*sc;
}

// ---------------- fp32 linear: 128 rows x 128 out per block, 8x8 micro-tile ----------------
// (256,2): cap 256 VGPR — (256,4)=128 cap spilled the accumulator (round-5 regression)
template<int K, bool CATF, bool BNF, bool TANHF, bool STATSF, int POOLM>
__global__ __launch_bounds__(256, 2)
void linear_kernel(const float* X, const float* __restrict__ X2,
                   const float* __restrict__ W, const float* __restrict__ bias,
                   float* Y,
                   const float* __restrict__ bnsc, const float* __restrict__ bnsh,
                   float* __restrict__ stats, float* __restrict__ pool){
  __shared__ __align__(16) float xs[32][132];
  __shared__ __align__(16) float ws[32][132];
  __shared__ float ssum[128], ssq[128];
  const int t = threadIdx.x;
  const int row0 = blockIdx.x*128;
  const int cg = t & 15, rg = t >> 4;
  const int c0 = cg*8, r0 = rg*8;
  float acc[8][8];
#pragma unroll
  for (int r=0;r<8;r++)
#pragma unroll
    for (int c=0;c<8;c++) acc[r][c]=0.f;
  if (STATSF && t < 128){ ssum[t]=0.f; ssq[t]=0.f; }

  for (int kc=0; kc<K; kc+=32){
    __syncthreads();
#pragma unroll
    for (int i=0;i<16;i++){
      int idx = t + 256*i;
      int k = idx & 31, r = idx >> 5;
      int gk = kc + k;
      int n = row0 + r;
      float v;
      if (CATF){
        v = (gk < 128) ? X[(size_t)n*128 + gk] : X2[(size_t)(n/NPGc)*128 + (gk-128)];
      } else {
        v = X[(size_t)n*K + gk];
      }
      if (BNF) v = fmaxf(0.f, v*bnsc[gk] + bnsh[gk]);
      xs[k][r] = v;
    }
#pragma unroll
    for (int i=0;i<16;i++){
      int idx = t + 256*i;
      int c = idx & 127, k = idx >> 7;
      ws[k][c] = W[(size_t)(kc+k)*128 + c];
    }
    __syncthreads();
#pragma unroll
    for (int k=0;k<32;k++){
      float4 xa = *(const float4*)&xs[k][r0];
      float4 xb = *(const float4*)&xs[k][r0+4];
      float4 wa = *(const float4*)&ws[k][c0];
      float4 wb = *(const float4*)&ws[k][c0+4];
      float xv[8] = {xa.x,xa.y,xa.z,xa.w,xb.x,xb.y,xb.z,xb.w};
      float wv[8] = {wa.x,wa.y,wa.z,wa.w,wb.x,wb.y,wb.z,wb.w};
#pragma unroll
      for (int r=0;r<8;r++)
#pragma unroll
        for (int c=0;c<8;c++)
          acc[r][c] += xv[r]*wv[c];
    }
  }
  float4 ba = *(const float4*)(bias + c0);
  float4 bb2 = *(const float4*)(bias + c0 + 4);
  float bv[8] = {ba.x,ba.y,ba.z,ba.w,bb2.x,bb2.y,bb2.z,bb2.w};
  float sc8[8], sq8[8];
#pragma unroll
  for (int c=0;c<8;c++){ sc8[c]=0.f; sq8[c]=0.f; }
#pragma unroll
  for (int r=0;r<8;r++){
    int n = row0 + r0 + r;
    float y[8];
#pragma unroll
    for (int c=0;c<8;c++){
      float v = acc[r][c] + bv[c];
      if (TANHF) v = fast_tanh(v);
      y[c] = v;
    }
    float4 y0; y0.x=y[0]; y0.y=y[1]; y0.z=y[2]; y0.w=y[3];
    float4 y1; y1.x=y[4]; y1.y=y[5]; y1.z=y[6]; y1.w=y[7];
    *(float4*)(Y + (size_t)n*128 + c0)     = y0;
    *(float4*)(Y + (size_t)n*128 + c0 + 4) = y1;
    if (POOLM == 1){
      *(float4*)(pool + (size_t)n*128 + c0)     = y0;
      *(float4*)(pool + (size_t)n*128 + c0 + 4) = y1;
    } else if (POOLM == 2){
      float4 p0 = *(const float4*)(pool + (size_t)n*128 + c0);
      float4 p1 = *(const float4*)(pool + (size_t)n*128 + c0 + 4);
      p0.x+=y[0]; p0.y+=y[1]; p0.z+=y[2]; p0.w+=y[3];
      p1.x+=y[4]; p1.y+=y[5]; p1.z+=y[6]; p1.w+=y[7];
      *(float4*)(pool + (size_t)n*128 + c0)     = p0;
      *(float4*)(pool + (size_t)n*128 + c0 + 4) = p1;
    }
    if (STATSF){
#pragma unroll
      for (int c=0;c<8;c++){ sc8[c]+=y[c]; sq8[c]+=y[c]*y[c]; }
    }
  }
  if (STATSF){
#pragma unroll
    for (int c=0;c<8;c++){
      atomicAdd(&ssum[c0+c], sc8[c]);
      atomicAdd(&ssq[c0+c],  sq8[c]);
    }
    __syncthreads();
    if (t < 128){
      atomicAdd(&stats[t],     ssum[t]);
      atomicAdd(&stats[128+t], ssq[t]);
    }
  }
}

// ---------------- graph pool (mean of node_pool per graph) ----------------
__global__ void gpool_kernel(const float* __restrict__ pool, float* __restrict__ gpool){
  int b = blockIdx.x, f = threadIdx.x;
  const float* p = pool + (size_t)b*NPGc*128 + f;
  float s = 0.f;
  for (int i=0;i<NPGc;i++) s += p[(size_t)i*128];
  gpool[(size_t)b*128 + f] = s * (1.0f/NPGc);
}

// ---------------- triangle scores: s=A.A^T symmetric; tile-pairs tn<=tm only ----------------
// For n<m both directions share one score s: softmax adds cnt*exp, argmax pushes both ids.
#define QCAP 1024
#define NPAIR 36

__global__ __launch_bounds__(256)
void scores_tri_kernel(const float* __restrict__ A, const unsigned char* __restrict__ mask_u8,
                       const int* __restrict__ mask_i32, const unsigned char* __restrict__ mt8,
                       const int* __restrict__ mflag, float* __restrict__ partials){
  __shared__ __align__(16) float as[128][68];
  __shared__ __align__(16) float bs[32][68];
  __shared__ float qs[QCAP];
  __shared__ int   qi[QCAP];
  __shared__ int   qcnt;
  float* rm  = qs;
  float* rs_ = qs + 256;
  float* rv  = qs + 512;
  float* rsc = qs + 768;
  int*   ri  = qi;
  const int t = threadIdx.x;
  const int b = blockIdx.y;
  // decode pair index -> (tn, tm), tn <= tm
  int pidx = blockIdx.x, tn = 0;
  while (pidx >= 8 - tn){ pidx -= 8 - tn; tn++; }
  const int tm = tn + pidx;
  const bool diag = (tn == tm);
  const int n0 = tn*64, m0 = tm*64;
  const int cgc = t & 15, rgc = t >> 4;
  const int r0_ = rgc*4, c0 = cgc*4;
  const float* Ab = A + (size_t)b*NPGc*128;
  const unsigned gbase = (unsigned)b*250000u;
  const int isbool = *mflag;
  if (t == 0) qcnt = 0;

  // stage row tile (64 rows, K=128, k-major)
#pragma unroll
  for (int i=0;i<32;i++){
    int idx = t + 256*i;
    int k = idx & 127, r = idx >> 7;
    int n = n0 + r;
    as[k][r] = (n < NPGc) ? Ab[(size_t)n*128 + k] : 0.f;
  }

  float acc[4][4];
#pragma unroll
  for (int i2=0;i2<4;i2++)
#pragma unroll
    for (int j=0;j<4;j++) acc[i2][j]=0.f;

  for (int kc=0;kc<4;kc++){
    __syncthreads();
#pragma unroll
    for (int i=0;i<8;i++){
      int idx = t + 256*i;
      int kk = idx & 31, c = idx >> 5;
      int m = m0 + c;
      bs[kk][c] = (m < NPGc) ? Ab[(size_t)m*128 + kc*32 + kk] : 0.f;
    }
    __syncthreads();
#pragma unroll
    for (int kk=0;kk<32;kk++){
      float4 av = *(const float4*)&as[kc*32+kk][r0_];
      float4 bv4 = *(const float4*)&bs[kk][c0];
      float a_[4] = {av.x,av.y,av.z,av.w};
      float b_[4] = {bv4.x,bv4.y,bv4.z,bv4.w};
#pragma unroll
      for (int i2=0;i2<4;i2++)
#pragma unroll
        for (int j=0;j<4;j++)
          acc[i2][j] += a_[i2]*b_[j];
    }
  }

  float mrun = -1e30f, srun = 0.f, bval = -FLT_MAX, bsc = 0.f;
  int bidx = 0x7FFFFFFF;
  const int mbase = m0 + c0;
  const bool colok = (mbase < NPGc);
#pragma unroll
  for (int i2=0;i2<4;i2++){
    int n = n0 + r0_ + i2;
    bool rowok = colok && (n < NPGc);
    bool fn[4] = {false,false,false,false};
    bool fm[4] = {false,false,false,false};
    if (rowok){
      size_t moff = (size_t)b*250000 + (size_t)n*500 + (size_t)mbase;
      if (isbool){
        uchar4 mk = *(const uchar4*)(mask_u8 + moff);
        fn[0]=mk.x!=0; fn[1]=mk.y!=0; fn[2]=mk.z!=0; fn[3]=mk.w!=0;
      } else {
        int4 mk = *(const int4*)(mask_i32 + moff);
        fn[0]=mk.x!=0; fn[1]=mk.y!=0; fn[2]=mk.z!=0; fn[3]=mk.w!=0;
      }
      uchar4 tk = *(const uchar4*)(mt8 + moff);   // mt8[b][n][m] = mask[b][m][n]
      fm[0]=tk.x!=0; fm[1]=tk.y!=0; fm[2]=tk.z!=0; fm[3]=tk.w!=0;
    }
    float cntj[4], sj[4];
    bool pn[4], pm[4];
#pragma unroll
    for (int j=0;j<4;j++){
      int m = mbase + j;
      bool mok = rowok && (m < NPGc);
      bool keep = mok && (!diag || m >= n);
      bool isde = (n == m);
      float cnt = 0.f; bool a1=false, a2=false;
      if (keep){
        if (isde){ cnt = fn[j] ? 1.f : 0.f; a1 = fn[j]; }
        else { cnt = (fn[j]?1.f:0.f) + (fm[j]?1.f:0.f); a1 = fn[j]; a2 = fm[j]; }
      }
      cntj[j]=cnt; pn[j]=a1; pm[j]=a2;
      sj[j] = (cnt > 0.f) ? acc[i2][j] : -1e30f;
    }
    float tmx = fmaxf(fmaxf(sj[0],sj[1]), fmaxf(sj[2],sj[3]));
    float nm = fmaxf(mrun, tmx);
    float add = 0.f;
#pragma unroll
    for (int j=0;j<4;j++) add += cntj[j]*__expf(sj[j] - nm);
    srun = srun*__expf(mrun - nm) + add;
    mrun = nm;
#pragma unroll
    for (int j=0;j<4;j++){
      int m = mbase + j;
      if (pn[j] || pm[j]){
        float s = acc[i2][j];
#pragma unroll
        for (int d=0;d<2;d++){
          bool doit = d ? pm[j] : pn[j];
          if (doit){
            int lidx = d ? (m*500 + n) : (n*500 + m);
            int slot = atomicAdd(&qcnt, 1);
            if (slot < QCAP){ qs[slot] = s; qi[slot] = lidx; }
            else {
              float g = gumbel_of(gbase + (unsigned)lidx);
              float val = s + g;
              if (val > bval || (val == bval && lidx < bidx)){ bval = val; bidx = lidx; bsc = s; }
            }
          }
        }
      }
    }
  }
  // single drain, full-lane utilization
  __syncthreads();
  int qn = qcnt; if (qn > QCAP) qn = QCAP;
  for (int i = t; i < qn; i += 256){
    float s = qs[i]; int idx = qi[i];
    float g = gumbel_of(gbase + (unsigned)idx);
    float val = s + g;
    if (val > bval || (val == bval && idx < bidx)){ bval = val; bidx = idx; bsc = s; }
  }
  __syncthreads();
  rm[t]=mrun; rs_[t]=srun; rv[t]=bval; ri[t]=bidx; rsc[t]=bsc;
  __syncthreads();
  for (int offr=128; offr>0; offr>>=1){
    if (t < offr){
      float m1 = rm[t], s1 = rs_[t];
      float m2 = rm[t+offr], s2 = rs_[t+offr];
      float M = fmaxf(m1, m2);
      float S = s1*expf(m1-M) + s2*expf(m2-M);
      rm[t] = M; rs_[t] = S;
      float v2 = rv[t+offr]; int i2_ = ri[t+offr];
      if (v2 > rv[t] || (v2 == rv[t] && i2_ < ri[t])){ rv[t]=v2; ri[t]=i2_; rsc[t]=rsc[t+offr]; }
    }
    __syncthreads();
  }
  if (t == 0){
    float* p = partials + ((size_t)b*NPAIR + blockIdx.x)*8;
    p[0]=rm[0]; p[1]=rs_[0]; p[2]=rv[0]; p[3]=(float)ri[0]; p[4]=rsc[0];
  }
}

__global__ void finalize_kernel(const float* __restrict__ partials, float* __restrict__ out){
  int b = threadIdx.x;
  float M = -1e30f, S = 0.f, BV = -FLT_MAX, BS = 0.f;
  int BI = 0x7FFFFFFF;
  for (int tp=0; tp<NPAIR; tp++){
    const float* p = partials + ((size_t)b*NPAIR + tp)*8;
    float m = p[0], s = p[1], v = p[2]; int i = (int)p[3]; float sc2 = p[4];
    float nM = fmaxf(M, m);
    S = S*expf(M-nM) + s*expf(m-nM);
    M = nM;
    if (v > BV || (v == BV && i < BI)){ BV = v; BI = i; BS = sc2; }
  }
  out[b]      = (float)BI;
  out[BB + b] = BS - (M + logf(S));
}

// ---------------- host launch ----------------
extern "C" void kernel_launch(void* const* d_in, const int* in_sizes, int n_in,
                              void* d_out, int out_size, void* d_ws, size_t ws_size,
                              hipStream_t stream){
  const float* x        = (const float*)d_in[0];
  const int*   eidx     = (const int*)d_in[1];
  const void*  maskp    = d_in[3];
  const float* gin_W1_0 = (const float*)d_in[4];
  const float* gin_b1_0 = (const float*)d_in[5];
  const float* gin_g_0  = (const float*)d_in[6];
  const float* gin_be_0 = (const float*)d_in[7];
  const float* gin_W2_0 = (const float*)d_in[8];
  const float* gin_b2_0 = (const float*)d_in[9];
  const float* gin_W1   = (const float*)d_in[10];
  const float* gin_b1   = (const float*)d_in[11];
  const float* gin_g    = (const float*)d_in[12];
  const float* gin_be   = (const float*)d_in[13];
  const float* gin_W2   = (const float*)d_in[14];
  const float* gin_b2   = (const float*)d_in[15];
  const float* pol_W1_0 = (const float*)d_in[16];
  const float* pol_b1_0 = (const float*)d_in[17];
  const float* pol_W2_0 = (const float*)d_in[18];
  const float* pol_b2_0 = (const float*)d_in[19];
  const float* pol_W1   = (const float*)d_in[20];
  const float* pol_b1   = (const float*)d_in[21];
  const float* pol_W2   = (const float*)d_in[22];
  const float* pol_b2   = (const float*)d_in[23];
  float* out = (float*)d_out;

  char* p = (char*)d_ws;
  auto carve = [&](size_t bytes) -> void* {
    void* r = (void*)p; p += (bytes + 255) & ~(size_t)255; return r;
  };
  float* hbuf  = (float*)carve((size_t)NN*128*4);
  float* xin   = (float*)carve((size_t)NN*128*4);
  float* pool  = (float*)carve((size_t)NN*128*4);
  float* xin0  = (float*)carve((size_t)NN*3*4);
  float* gpool = (float*)carve((size_t)BB*128*4);
  float* dinv  = (float*)carve((size_t)NN*4);
  float* stats = (float*)carve(256*4);
  float* bnbuf = (float*)carve(256*4);
  float* partials = (float*)carve((size_t)BB*NPAIR*8*4);
  int* cnt = (int*)carve((size_t)NN*4);
  int* off = (int*)carve((size_t)(NN+1)*4);
  int* cur = (int*)carve((size_t)NN*4);
  int* csr = (int*)carve((size_t)EE*4);
  int* mflag = (int*)carve(256);
  unsigned char* mt8 = (unsigned char*)carve((size_t)BB*250000);

  const int* srcp = eidx;
  const int* dstp = eidx + EE;

  maskdet_kernel<<<1, 64, 0, stream>>>((const unsigned*)maskp, mflag);
  {
    dim3 mg(64, BB);
    maskprep_kernel<<<mg, 256, 0, stream>>>((const unsigned char*)maskp, (const int*)maskp,
                                            mflag, mt8);
  }

  hipMemsetAsync(cnt, 0, (size_t)NN*4, stream);
  count_kernel<<<(EE+255)/256, 256, 0, stream>>>(dstp, cnt);
  scan_kernel<<<1, 1024, 0, stream>>>(cnt, off, cur);
  fill_kernel<<<(EE+255)/256, 256, 0, stream>>>(srcp, dstp, cur, csr);
  dinv_kernel<<<(NN+255)/256, 256, 0, stream>>>(cnt, dinv);

  // GIN layer 0
  agg3_kernel<<<(NN+255)/256, 256, 0, stream>>>(x, off, csr, dinv, xin0);
  hipMemsetAsync(stats, 0, 256*4, stream);
  z0_kernel<<<NN/64, 256, 0, stream>>>(xin0, gin_W1_0, gin_b1_0, xin, stats);
  bnfin_kernel<<<1, 128, 0, stream>>>(stats, gin_g_0, gin_be_0, bnbuf);
  linear_kernel<128,false,true,false,false,1><<<NN/128, 256, 0, stream>>>(
      xin, nullptr, gin_W2_0, gin_b2_0, hbuf, bnbuf, bnbuf+128, nullptr, pool);

  // GIN layers 1..3
  for (int l=0; l<3; l++){
    agg128_kernel<<<NN/4, 256, 0, stream>>>(hbuf, off, csr, dinv, xin);
    hipMemsetAsync(stats, 0, 256*4, stream);
    linear_kernel<128,false,false,false,true,0><<<NN/128, 256, 0, stream>>>(
        xin, nullptr, gin_W1 + (size_t)l*16384, gin_b1 + l*128, xin,
        nullptr, nullptr, stats, nullptr);
    bnfin_kernel<<<1, 128, 0, stream>>>(stats, gin_g + l*128, gin_be + l*128, bnbuf);
    linear_kernel<128,false,true,false,false,2><<<NN/128, 256, 0, stream>>>(
        xin, nullptr, gin_W2 + (size_t)l*16384, gin_b2 + l*128, hbuf,
        bnbuf, bnbuf+128, nullptr, pool);
  }

  // policy MLP
  gpool_kernel<<<BB, 128, 0, stream>>>(pool, gpool);
  linear_kernel<256,true,false,true,false,0><<<NN/128, 256, 0, stream>>>(
      pool, gpool, pol_W1_0, pol_b1_0, hbuf, nullptr, nullptr, nullptr, nullptr);
  linear_kernel<128,false,false,false,false,0><<<NN/128, 256, 0, stream>>>(
      hbuf, nullptr, pol_W2_0, pol_b2_0, xin, nullptr, nullptr, nullptr, nullptr);
  linear_kernel<128,false,false,true,false,0><<<NN/128, 256, 0, stream>>>(
      xin, nullptr, pol_W1, pol_b1, hbuf, nullptr, nullptr, nullptr, nullptr);
  linear_kernel<128,false,false,false,false,0><<<NN/128, 256, 0, stream>>>(
      hbuf, nullptr, pol_W2, pol_b2, xin, nullptr, nullptr, nullptr, nullptr);
  linear_kernel<128,false,false,true,false,0><<<NN/128, 256, 0, stream>>>(
      xin, nullptr, pol_W1 + 16384, pol_b1 + 128, hbuf, nullptr, nullptr, nullptr, nullptr);
  linear_kernel<128,false,false,false,false,0><<<NN/128, 256, 0, stream>>>(
      hbuf, nullptr, pol_W2 + 16384, pol_b2 + 128, xin, nullptr, nullptr, nullptr, nullptr);

  // scores + sampling (triangle)
  dim3 sg(NPAIR, BB);
  scores_tri_kernel<<<sg, 256, 0, stream>>>(xin, (const unsigned char*)maskp,
                                            (const int*)maskp, mt8, mflag, partials);
  finalize_kernel<<<1, BB, 0, stream>>>(partials, out);
}